// Round 11
// baseline (1651.868 us; speedup 1.0000x reference)
//
#include <hip/hip_runtime.h>

#define N_TOK 16384
#define ALPHA_LRELU 0.2f
#define NEGV -9e15f
#define NSPLIT 4
#define LOG2E 1.44269504f
#define DEFER_THR 8.0f

typedef _Float16 f16;
typedef __attribute__((ext_vector_type(8))) _Float16 f16x8;
typedef __attribute__((ext_vector_type(4))) float f32x4;
typedef __attribute__((ext_vector_type(4))) int i32x4;
typedef unsigned short u16;

__device__ __forceinline__ float bf2f(u16 b) {
  unsigned u = ((unsigned)b) << 16;
  return __builtin_bit_cast(float, u);
}
__device__ __forceinline__ f16x8 cvt8(i32x4 v) {
  f16x8 r;
#pragma unroll
  for (int i = 0; i < 4; ++i) {
    unsigned u = __builtin_bit_cast(unsigned, v[i]);
    r[2 * i]     = (f16)__builtin_bit_cast(float, (u & 0xffffu) << 16);
    r[2 * i + 1] = (f16)__builtin_bit_cast(float, u & 0xffff0000u);
  }
  return r;
}

// HBM -> LDS direct DMA, 16 B/lane. LDS dest is wave-uniform base + lane*16.
__device__ __forceinline__ void gload16(const void* g, void* l) {
  __builtin_amdgcn_global_load_lds(
      (const __attribute__((address_space(1))) unsigned*)g,
      (__attribute__((address_space(3))) unsigned*)l, 16, 0, 0);
}

// ---------------- kernel 0: input dtype detection (EVEN u16 parity) ----
__global__ __launch_bounds__(64) void detect_kernel(const u16* __restrict__ h16,
                                                    int* __restrict__ flag)
{
  int lane = threadIdx.x;
  unsigned u = h16[lane * 2];
  unsigned e = (u >> 7) & 0xFFu;
  int sane = (e >= 0x60u && e <= 0x8Eu) ? 1 : 0;
#pragma unroll
  for (int off = 32; off >= 1; off >>= 1) sane += __shfl_xor(sane, off);
  if (lane == 0) *flag = (sane >= 32) ? 1 : 0;  // 1 = bf16 inputs, 0 = fp32
}

// ---------------- kernel 0.5: ws-too-small sentinel ----------------
__global__ __launch_bounds__(256) void sentinel_kernel(float* __restrict__ out) {
  int i = blockIdx.x * 256 + threadIdx.x;
  if (i < N_TOK * 128) out[i] = 100.0f;
}

// ---------------- kernel 1: W transpose -> fp16 ----------------
// W_query additionally scaled by log2(e): scores arrive in log2 domain
// (leakyrelu commutes with positive scaling), so softmax uses exp2 directly.
__global__ __launch_bounds__(256) void wt_kernel(
    const int* __restrict__ flag,
    const void* __restrict__ Wq, const void* __restrict__ Wk,
    const void* __restrict__ Wv, f16* __restrict__ Wt)
{
  const int isbf = *flag;
  int w = blockIdx.y;
  const void* W = (w == 0) ? Wq : (w == 1) ? Wk : Wv;
  int idx = blockIdx.x * 256 + threadIdx.x;
  int k = idx >> 7, n = idx & 127;
  float v = isbf ? bf2f(((const u16*)W)[idx]) : ((const float*)W)[idx];
  if (w == 0) v *= LOG2E;
  Wt[w * 32768 + n * 256 + k] = (f16)v;
}

// ---------------- kernel 2: fused QKV GEMM ----------------
__global__ __launch_bounds__(256) void qkv_kernel(
    const int* __restrict__ flag, const void* __restrict__ hvp,
    const f16* __restrict__ Wt,
    f16* __restrict__ Qo, f16* __restrict__ Ko, f16* __restrict__ Vt)
{
  const int isbf = *flag;
  const int mb = blockIdx.x * 64;
  const int gy = blockIdx.y;
  const int tid = threadIdx.x;
  const int wave = tid >> 6, lane = tid & 63, quad = lane >> 4, l16 = lane & 15;

  __shared__ __align__(16) f16 hs[64][256 + 8];

  if (isbf) {
    const u16* h = (const u16*)hvp;
#pragma unroll
    for (int i = 0; i < 8; ++i) {
      int c = i * 256 + tid;
      int r = c >> 5, o = c & 31;
      i32x4 v = *(const i32x4*)(h + (size_t)(mb + r) * 256 + o * 8);
      *(f16x8*)(&hs[r][o * 8]) = cvt8(v);
    }
  } else {
    const float* h = (const float*)hvp;
#pragma unroll
    for (int i = 0; i < 8; ++i) {
      int c = i * 256 + tid;
      int r = c >> 5, o = c & 31;
      const float* p = h + (size_t)(mb + r) * 256 + o * 8;
      f32x4 v0 = *(const f32x4*)p, v1 = *(const f32x4*)(p + 4);
      f16x8 q;
#pragma unroll
      for (int j = 0; j < 4; ++j) { q[j] = (f16)v0[j]; q[4 + j] = (f16)v1[j]; }
      *(f16x8*)(&hs[r][o * 8]) = q;
    }
  }
  __syncthreads();

  const f16* Wg = Wt + gy * 32768;

  if (gy < 2) {
    f16x8 a[8];
#pragma unroll
    for (int ks = 0; ks < 8; ++ks)
      a[ks] = *(const f16x8*)(&hs[wave * 16 + l16][ks * 32 + quad * 8]);
    f32x4 acc[8];
#pragma unroll
    for (int ct = 0; ct < 8; ++ct) acc[ct] = (f32x4){0.f, 0.f, 0.f, 0.f};
#pragma unroll
    for (int ks = 0; ks < 8; ++ks)
#pragma unroll
      for (int ct = 0; ct < 8; ++ct) {
        f16x8 b = *(const f16x8*)(Wg + (ct * 16 + l16) * 256 + ks * 32 + quad * 8);
        acc[ct] = __builtin_amdgcn_mfma_f32_16x16x32_f16(a[ks], b, acc[ct], 0, 0, 0);
      }
    f16* O = (gy == 0) ? Qo : Ko;
#pragma unroll
    for (int ct = 0; ct < 8; ++ct)
#pragma unroll
      for (int r = 0; r < 4; ++r)
        O[(size_t)(mb + wave * 16 + quad * 4 + r) * 128 + ct * 16 + l16] = (f16)acc[ct][r];
  } else {
    f32x4 acc[2][4];
#pragma unroll
    for (int ft = 0; ft < 2; ++ft)
#pragma unroll
      for (int bt = 0; bt < 4; ++bt) acc[ft][bt] = (f32x4){0.f, 0.f, 0.f, 0.f};
#pragma unroll
    for (int ks = 0; ks < 8; ++ks) {
      f16x8 a2[2], b2[4];
#pragma unroll
      for (int ft = 0; ft < 2; ++ft)
        a2[ft] = *(const f16x8*)(Wg + ((wave * 2 + ft) * 16 + l16) * 256 + ks * 32 + quad * 8);
#pragma unroll
      for (int bt = 0; bt < 4; ++bt)
        b2[bt] = *(const f16x8*)(&hs[bt * 16 + l16][ks * 32 + quad * 8]);
#pragma unroll
      for (int ft = 0; ft < 2; ++ft)
#pragma unroll
        for (int bt = 0; bt < 4; ++bt)
          acc[ft][bt] = __builtin_amdgcn_mfma_f32_16x16x32_f16(a2[ft], b2[bt], acc[ft][bt], 0, 0, 0);
    }
#pragma unroll
    for (int ft = 0; ft < 2; ++ft)
#pragma unroll
      for (int bt = 0; bt < 4; ++bt)
#pragma unroll
        for (int r = 0; r < 4; ++r)
          Vt[(size_t)((wave * 2 + ft) * 16 + quad * 4 + r) * N_TOK + mb + bt * 16 + l16] =
              (f16)acc[ft][bt][r];
  }
}

// ---------------- kernel 3: flash attention, 4 blocks/CU ----------------
// R11: push occupancy 3 -> 4 blocks/CU.
//  * Ps padded [4][16][72] (9216 B) -> swizzled unpadded PsL (8192 B):
//    write byte = row*128 + ((col*2) ^ ((row&7)<<4)); read applies the same
//    XOR (16B blocks, bits 4-6 only) -> LDS total 40960 B = 163840/4 exactly.
//  * masks: 16 loads live only issue->pack (covered by PV); steady state is
//    ONE packed register amp (bit ct*4+r) -> state fits (256,4) cap = 128.
//  * 2 raw barriers/iter, both vmcnt(0): barrier A's drains V(t) (covered
//    by QK), barrier B's drains K(t+1)+masks (covered by PV). Robust to
//    compiler issue reordering (no counted-N race on the K DMA).
//  * setprio(1) around both MFMA clusters (T5; phase-split structure).
// Tripwires: WRITE_SIZE >> 34MB = spill -> revert to R10; Occ ~35% = LDS
// or reg accounting wrong.
__global__ __launch_bounds__(256, 4) void flash_kernel(
    const f16* __restrict__ Q, const f16* __restrict__ Kg,
    const f16* __restrict__ Vt, const int* __restrict__ adj,
    float* __restrict__ Opart, float* __restrict__ mpart,
    float* __restrict__ lpart)
{
  const int qb = blockIdx.x * 64;
  const int ksec = blockIdx.y;
  const int iters = 256 / NSPLIT;        // 64
  const int kb0 = ksec * iters * 64;
  const int tid = threadIdx.x;
  const int wave = tid >> 6, lane = tid & 63, quad = lane >> 4, l16 = lane & 15;

  __shared__ __align__(16) f16 KsL[64 * 128];   // linear, 256 B rows
  __shared__ __align__(16) f16 VsL[128 * 64];   // linear, 128 B rows
  __shared__ __align__(16) f16 PsL[4 * 16 * 64]; // swizzled, 128 B rows

  const int swl = (l16 & 7) << 4;  // read-side XOR

  f16x8 qf[4];
#pragma unroll
  for (int ks = 0; ks < 4; ++ks)
    qf[ks] = *(const f16x8*)(Q + (size_t)(qb + wave * 16 + l16) * 128 + ks * 32 + quad * 8);

  f16x8 ONES;
#pragma unroll
  for (int j = 0; j < 8; ++j) ONES[j] = (f16)1.0f;

  const int* aprow[4];
#pragma unroll
  for (int r = 0; r < 4; ++r)
    aprow[r] = adj + (size_t)(qb + wave * 16 + quad * 4 + r) * N_TOK + l16;

  f32x4 Oacc[8];
#pragma unroll
  for (int ot = 0; ot < 8; ++ot) Oacc[ot] = (f32x4){0.f, 0.f, 0.f, 0.f};
  f32x4 Lacc = (f32x4){0.f, 0.f, 0.f, 0.f};
  float m2[4];
#pragma unroll
  for (int r = 0; r < 4; ++r) m2[r] = -INFINITY;

  unsigned amp;  // packed adjacency bits for CURRENT tile: bit ct*4+r

  const char* Kc = (const char*)Kg;
  const char* Vc = (const char*)Vt;
  char* Kl = (char*)KsL;
  char* Vl = (char*)VsL;

#define STAGE_K(KB)                                                           \
  {                                                                           \
    int kb_ = (KB);                                                           \
    _Pragma("unroll")                                                         \
    for (int i = 0; i < 4; ++i) {                                             \
      int row = i * 16 + (tid >> 4);                                          \
      int colb = ((tid & 15) * 16) ^ ((row & 7) << 4);                        \
      gload16(Kc + (size_t)(kb_ + row) * 256 + colb,                          \
              Kl + i * 4096 + wave * 1024);                                   \
    }                                                                         \
  }
#define STAGE_V(KB)                                                           \
  {                                                                           \
    int kb_ = (KB);                                                           \
    _Pragma("unroll")                                                         \
    for (int i = 0; i < 4; ++i) {                                             \
      int d = i * 32 + (tid >> 3);                                            \
      int colb = ((tid & 7) * 16) ^ ((d & 7) << 4);                           \
      gload16(Vc + (size_t)d * (N_TOK * 2) + (size_t)kb_ * 2 + colb,          \
              Vl + i * 4096 + wave * 1024);                                   \
    }                                                                         \
  }

  // -------- prologue: DMA tile0, masks tile0, full drain, pack --------
  STAGE_K(kb0);
  STAGE_V(kb0);
  {
    int mi[16];
#pragma unroll
    for (int ct = 0; ct < 4; ++ct)
#pragma unroll
      for (int r = 0; r < 4; ++r)
        mi[ct * 4 + r] = aprow[r][kb0 + ct * 16];
    asm volatile("s_waitcnt vmcnt(0)" ::: "memory");
    unsigned na = 0;
#pragma unroll
    for (int j = 0; j < 16; ++j) na |= (unsigned)(mi[j] > 0) << j;
    amp = na;
  }
  __builtin_amdgcn_s_barrier();
  asm volatile("" ::: "memory");

  for (int it = 0; it < iters; ++it) {
    const int kbn = kb0 + (it + 1) * 64;

    // --- QK^T from swizzled K tile; leakyrelu; mask bits from amp ---
    float sc[4][4];
    __builtin_amdgcn_s_setprio(1);
#pragma unroll
    for (int ct = 0; ct < 4; ++ct) {
      f32x4 s = (f32x4){0.f, 0.f, 0.f, 0.f};
#pragma unroll
      for (int ks = 0; ks < 4; ++ks) {
        f16x8 b = *(const f16x8*)((const char*)KsL + (ct * 16 + l16) * 256 +
                                  ((ks * 64 + quad * 16) ^ swl));
        s = __builtin_amdgcn_mfma_f32_16x16x32_f16(qf[ks], b, s, 0, 0, 0);
      }
#pragma unroll
      for (int r = 0; r < 4; ++r) {
        float v = s[r];
        v = fmaxf(v, ALPHA_LRELU * v);
        sc[ct][r] = ((amp >> (ct * 4 + r)) & 1u) ? v : NEGV;
      }
    }
    __builtin_amdgcn_s_setprio(0);

    // --- row max + defer-max rescale (register-only) ---
    float mx[4];
#pragma unroll
    for (int r = 0; r < 4; ++r) {
      float m = fmaxf(fmaxf(sc[0][r], sc[1][r]), fmaxf(sc[2][r], sc[3][r]));
#pragma unroll
      for (int off = 8; off >= 1; off >>= 1)
        m = fmaxf(m, __shfl_xor(m, off, 16));
      mx[r] = m;
    }
    bool up = (mx[0] > m2[0] + DEFER_THR) | (mx[1] > m2[1] + DEFER_THR) |
              (mx[2] > m2[2] + DEFER_THR) | (mx[3] > m2[3] + DEFER_THR);
    if (__ballot(up)) {
      float al[4];
#pragma unroll
      for (int r = 0; r < 4; ++r) {
        float mn = fmaxf(m2[r], mx[r]);
        al[r] = exp2f(m2[r] - mn);
        m2[r] = mn;
      }
#pragma unroll
      for (int ot = 0; ot < 8; ++ot)
#pragma unroll
        for (int r = 0; r < 4; ++r) Oacc[ot][r] *= al[r];
#pragma unroll
      for (int r = 0; r < 4; ++r) Lacc[r] *= al[r];
    }

    // --- barrier A: Ks reads done everywhere; V(t) DMA visible ---
    asm volatile("s_waitcnt vmcnt(0) lgkmcnt(0)" ::: "memory");
    __builtin_amdgcn_s_barrier();
    asm volatile("" ::: "memory");

    // --- issue K(t+1) DMA + mask loads (both fly during PV) ---
    int mi[16];
    if (it + 1 < iters) {
      STAGE_K(kbn);
#pragma unroll
      for (int ct = 0; ct < 4; ++ct)
#pragma unroll
        for (int r = 0; r < 4; ++r)
          mi[ct * 4 + r] = aprow[r][kbn + ct * 16];
    }

    // --- P -> PsL (swizzled), PV from VsL, Lacc ---
    {
      char* Pw = (char*)PsL + wave * 2048;
#pragma unroll
      for (int ct = 0; ct < 4; ++ct)
#pragma unroll
        for (int r = 0; r < 4; ++r) {
          int row = quad * 4 + r;
          int cb = ((ct * 16 + l16) * 2) ^ ((row & 7) << 4);
          *(f16*)(Pw + row * 128 + cb) = (f16)exp2f(sc[ct][r] - m2[r]);
        }
    }
    asm volatile("s_waitcnt lgkmcnt(0)" ::: "memory");
    {
      const char* Pr = (const char*)PsL + wave * 2048 + l16 * 128;
      f16x8 pa0 = *(const f16x8*)(Pr + ((quad * 16) ^ swl));
      f16x8 pa1 = *(const f16x8*)(Pr + ((64 + quad * 16) ^ swl));
      __builtin_amdgcn_s_setprio(1);
#pragma unroll
      for (int ot = 0; ot < 8; ++ot) {
        const char* vrow = (const char*)VsL + (ot * 16 + l16) * 128;
        f16x8 b0 = *(const f16x8*)(vrow + ((quad * 16) ^ swl));
        f16x8 b1 = *(const f16x8*)(vrow + ((64 + quad * 16) ^ swl));
        Oacc[ot] = __builtin_amdgcn_mfma_f32_16x16x32_f16(pa0, b0, Oacc[ot], 0, 0, 0);
        Oacc[ot] = __builtin_amdgcn_mfma_f32_16x16x32_f16(pa1, b1, Oacc[ot], 0, 0, 0);
      }
      Lacc = __builtin_amdgcn_mfma_f32_16x16x32_f16(pa0, ONES, Lacc, 0, 0, 0);
      Lacc = __builtin_amdgcn_mfma_f32_16x16x32_f16(pa1, ONES, Lacc, 0, 0, 0);
      __builtin_amdgcn_s_setprio(0);
    }

    // --- pack next masks (kills the 16 transient regs before barrier B) ---
    if (it + 1 < iters) {
      unsigned na = 0;
#pragma unroll
      for (int j = 0; j < 16; ++j) na |= (unsigned)(mi[j] > 0) << j;
      amp = na;
    }

    // --- barrier B: Vs reads done everywhere; K(t+1)+masks retired ---
    asm volatile("s_waitcnt vmcnt(0) lgkmcnt(0)" ::: "memory");
    __builtin_amdgcn_s_barrier();
    asm volatile("" ::: "memory");

    // --- issue V(t+1) DMA; drains at next iter's barrier A (QK covers) ---
    if (it + 1 < iters) {
      STAGE_V(kbn);
    }
  }
#undef STAGE_K
#undef STAGE_V

  float* Op = Opart + (size_t)ksec * (N_TOK * 128);
#pragma unroll
  for (int ot = 0; ot < 8; ++ot)
#pragma unroll
    for (int r = 0; r < 4; ++r) {
      int row = qb + wave * 16 + quad * 4 + r;
      Op[(size_t)row * 128 + ot * 16 + l16] = Oacc[ot][r];
    }
  if (l16 == 0) {
#pragma unroll
    for (int r = 0; r < 4; ++r) {
      int row = qb + wave * 16 + quad * 4 + r;
      mpart[ksec * N_TOK + row] = m2[r];   // log2-domain (deferred) max
      lpart[ksec * N_TOK + row] = Lacc[r];
    }
  }
}

// ---------------- kernel 4: split-K combine + elu (log2 domain) --------
__global__ __launch_bounds__(256) void combine_kernel(
    const float* __restrict__ Opart, const float* __restrict__ mpart,
    const float* __restrict__ lpart, float* __restrict__ out)
{
  const int qb = blockIdx.x * 64;
  const int t = threadIdx.x;
  __shared__ float sa[NSPLIT][64], sdn[64];
  if (t < 64) {
    float m = -INFINITY;
#pragma unroll
    for (int s = 0; s < NSPLIT; ++s) m = fmaxf(m, mpart[s * N_TOK + qb + t]);
    float dn = 0.f;
#pragma unroll
    for (int s = 0; s < NSPLIT; ++s) {
      float a = exp2f(mpart[s * N_TOK + qb + t] - m);
      sa[s][t] = a;
      dn += lpart[s * N_TOK + qb + t] * a;
    }
    sdn[t] = 1.0f / dn;
  }
  __syncthreads();
  float* Og = out + (size_t)qb * 128;
#pragma unroll
  for (int i = 0; i < 8; ++i) {
    int idx = (i * 256 + t) * 4;
    int row = idx >> 7;
    f32x4 acc = (f32x4){0.f, 0.f, 0.f, 0.f};
#pragma unroll
    for (int s = 0; s < NSPLIT; ++s) {
      f32x4 o = *(const f32x4*)(Opart + (size_t)s * (N_TOK * 128) + (size_t)qb * 128 + idx);
      float a = sa[s][row];
#pragma unroll
      for (int j = 0; j < 4; ++j) acc[j] += o[j] * a;
    }
    float dn = sdn[row];
    f32x4 v;
#pragma unroll
    for (int j = 0; j < 4; ++j) {
      float x = acc[j] * dn;
      v[j] = (x > 0.f) ? x : (__expf(x) - 1.f);
    }
    *(f32x4*)(Og + idx) = v;
  }
}

// ---------------- fallback: single-pass flash (ws too small) ----------
__global__ __launch_bounds__(256) void flash1_kernel(
    const f16* __restrict__ Q, const f16* __restrict__ Kg,
    const f16* __restrict__ Vt, const int* __restrict__ adj,
    float* __restrict__ out)
{
  const int qb = blockIdx.x * 64;
  const int tid = threadIdx.x;
  const int wave = tid >> 6, lane = tid & 63, quad = lane >> 4, l16 = lane & 15;

  __shared__ __align__(16) f16 Ks[64][136];
  __shared__ __align__(16) f16 Vs[128][72];
  __shared__ __align__(16) int As[64][68];
  __shared__ __align__(16) f16 Ps[4][16][72];

  f16x8 qf[4];
#pragma unroll
  for (int ks = 0; ks < 4; ++ks)
    qf[ks] = *(const f16x8*)(Q + (size_t)(qb + wave * 16 + l16) * 128 + ks * 32 + quad * 8);
  f16x8 ONES;
#pragma unroll
  for (int j = 0; j < 8; ++j) ONES[j] = (f16)1.0f;

  f32x4 Oacc[8];
#pragma unroll
  for (int ot = 0; ot < 8; ++ot) Oacc[ot] = (f32x4){0.f, 0.f, 0.f, 0.f};
  f32x4 Lacc = (f32x4){0.f, 0.f, 0.f, 0.f};
  float m2[4];
#pragma unroll
  for (int r = 0; r < 4; ++r) m2[r] = -INFINITY;

  i32x4 pK[4], pV[4], pA[4];
#pragma unroll
  for (int i = 0; i < 4; ++i) {
    int c = i * 256 + tid;
    pK[i] = *(const i32x4*)(Kg + (size_t)(c >> 4) * 128 + (c & 15) * 8);
    pV[i] = *(const i32x4*)(Vt + (size_t)(c >> 3) * N_TOK + (c & 7) * 8);
    pA[i] = *(const i32x4*)(adj + (size_t)(qb + (c >> 4)) * N_TOK + (c & 15) * 4);
  }

  for (int it = 0; it < 256; ++it) {
    __syncthreads();
#pragma unroll
    for (int i = 0; i < 4; ++i) {
      int c = i * 256 + tid;
      *(f16x8*)(&Ks[c >> 4][(c & 15) * 8]) = __builtin_bit_cast(f16x8, pK[i]);
      *(f16x8*)(&Vs[c >> 3][(c & 7) * 8])  = __builtin_bit_cast(f16x8, pV[i]);
      *(i32x4*)(&As[c >> 4][(c & 15) * 4]) = pA[i];
    }
    __syncthreads();
    if (it + 1 < 256) {
      int kb = (it + 1) * 64;
#pragma unroll
      for (int i = 0; i < 4; ++i) {
        int c = i * 256 + tid;
        pK[i] = *(const i32x4*)(Kg + (size_t)(kb + (c >> 4)) * 128 + (c & 15) * 8);
        pV[i] = *(const i32x4*)(Vt + (size_t)(c >> 3) * N_TOK + kb + (c & 7) * 8);
        pA[i] = *(const i32x4*)(adj + (size_t)(qb + (c >> 4)) * N_TOK + kb + (c & 15) * 4);
      }
    }
    float sc[4][4];
#pragma unroll
    for (int ct = 0; ct < 4; ++ct) {
      f32x4 s = (f32x4){0.f, 0.f, 0.f, 0.f};
#pragma unroll
      for (int ks = 0; ks < 4; ++ks) {
        f16x8 b = *(const f16x8*)(&Ks[ct * 16 + l16][ks * 32 + quad * 8]);
        s = __builtin_amdgcn_mfma_f32_16x16x32_f16(qf[ks], b, s, 0, 0, 0);
      }
#pragma unroll
      for (int r = 0; r < 4; ++r) {
        float v = s[r];
        v = fmaxf(v, ALPHA_LRELU * v);
        sc[ct][r] = (As[wave * 16 + quad * 4 + r][ct * 16 + l16] > 0) ? v : NEGV;
      }
    }
    float mx[4];
#pragma unroll
    for (int r = 0; r < 4; ++r) {
      float m = fmaxf(fmaxf(sc[0][r], sc[1][r]), fmaxf(sc[2][r], sc[3][r]));
#pragma unroll
      for (int off = 8; off >= 1; off >>= 1)
        m = fmaxf(m, __shfl_xor(m, off, 16));
      mx[r] = m;
    }
    bool up = (mx[0] > m2[0] + DEFER_THR) | (mx[1] > m2[1] + DEFER_THR) |
              (mx[2] > m2[2] + DEFER_THR) | (mx[3] > m2[3] + DEFER_THR);
    if (__ballot(up)) {
      float al[4];
#pragma unroll
      for (int r = 0; r < 4; ++r) {
        float mn = fmaxf(m2[r], mx[r]);
        al[r] = exp2f(m2[r] - mn);
        m2[r] = mn;
      }
#pragma unroll
      for (int ot = 0; ot < 8; ++ot)
#pragma unroll
        for (int r = 0; r < 4; ++r) Oacc[ot][r] *= al[r];
#pragma unroll
      for (int r = 0; r < 4; ++r) Lacc[r] *= al[r];
    }
#pragma unroll
    for (int ct = 0; ct < 4; ++ct)
#pragma unroll
      for (int r = 0; r < 4; ++r)
        Ps[wave][quad * 4 + r][ct * 16 + l16] = (f16)exp2f(sc[ct][r] - m2[r]);

    asm volatile("s_waitcnt lgkmcnt(0)" ::: "memory");
    f16x8 pa0 = *(const f16x8*)(&Ps[wave][l16][quad * 8]);
    f16x8 pa1 = *(const f16x8*)(&Ps[wave][l16][32 + quad * 8]);
#pragma unroll
    for (int ot = 0; ot < 8; ++ot) {
      f16x8 b0 = *(const f16x8*)(&Vs[ot * 16 + l16][quad * 8]);
      f16x8 b1 = *(const f16x8*)(&Vs[ot * 16 + l16][32 + quad * 8]);
      Oacc[ot] = __builtin_amdgcn_mfma_f32_16x16x32_f16(pa0, b0, Oacc[ot], 0, 0, 0);
      Oacc[ot] = __builtin_amdgcn_mfma_f32_16x16x32_f16(pa1, b1, Oacc[ot], 0, 0, 0);
    }
    Lacc = __builtin_amdgcn_mfma_f32_16x16x32_f16(pa0, ONES, Lacc, 0, 0, 0);
    Lacc = __builtin_amdgcn_mfma_f32_16x16x32_f16(pa1, ONES, Lacc, 0, 0, 0);
  }
#pragma unroll
  for (int ot = 0; ot < 8; ++ot)
#pragma unroll
    for (int r = 0; r < 4; ++r) {
      float v = Oacc[ot][r] / Lacc[r];
      v = (v > 0.f) ? v : (__expf(v) - 1.f);
      int row = qb + wave * 16 + quad * 4 + r;
      out[(size_t)row * 128 + ot * 16 + l16] = v;
    }
}

extern "C" void kernel_launch(void* const* d_in, const int* in_sizes, int n_in,
                              void* d_out, int out_size, void* d_ws, size_t ws_size,
                              hipStream_t stream)
{
  const void* h  = d_in[0];
  const int* adj = (const int*)d_in[1];
  const void* Wq = d_in[2];
  const void* Wk = d_in[3];
  const void* Wv = d_in[4];
  float* out = (float*)d_out;             // fp32 [16384][128]

  char* ws = (char*)d_ws;
  int* flag = (int*)ws;                    // @0
  f16* Wt = (f16*)(ws + 1024);             // 196608 B
  f16* Q  = (f16*)(ws + 262144);           // 4 MiB
  f16* K  = (f16*)(ws + 4456448);          // 4 MiB
  f16* Vt = (f16*)(ws + 8650752);          // 4 MiB -> 12845056
  float* Opart = (float*)(ws + 12845056);  // 4 x 16384 x 128 f32 = 32 MiB
  float* mpart = (float*)(ws + 46399488);  // 4 x 16384 f32 = 256 KiB
  float* lpart = (float*)(ws + 46661632);  // 4 x 16384 f32 -> 46923776
  const size_t NEED_BASE  = 12845056;
  const size_t NEED_SPLIT = 46923776;

  if (ws_size < NEED_BASE) {
    sentinel_kernel<<<(N_TOK * 128 + 255) / 256, 256, 0, stream>>>(out);
    return;
  }

  detect_kernel<<<1, 64, 0, stream>>>((const u16*)h, flag);
  wt_kernel<<<dim3(128, 3), 256, 0, stream>>>(flag, Wq, Wk, Wv, Wt);
  qkv_kernel<<<dim3(256, 3), 256, 0, stream>>>(flag, h, Wt, Q, K, Vt);

  if (ws_size >= NEED_SPLIT) {
    // split-K x4: 1024 blocks = 4 resident/CU (LDS 40960 B, (256,4) cap)
    flash_kernel<<<dim3(256, NSPLIT), 256, 0, stream>>>(Q, K, Vt, adj,
                                                        Opart, mpart, lpart);
    combine_kernel<<<dim3(256), 256, 0, stream>>>(Opart, mpart, lpart, out);
  } else {
    flash1_kernel<<<dim3(256), 256, 0, stream>>>(Q, K, Vt, adj, out);
  }
}

// Round 12
// 1477.839 us; speedup vs baseline: 1.1178x; 1.1178x over previous
//
#include <hip/hip_runtime.h>

#define N_TOK 16384
#define ALPHA_LRELU 0.2f
#define NEGV -9e15f
#define NSPLIT 3
#define LOG2E 1.44269504f
#define DEFER_THR 8.0f

typedef _Float16 f16;
typedef __attribute__((ext_vector_type(8))) _Float16 f16x8;
typedef __attribute__((ext_vector_type(4))) float f32x4;
typedef __attribute__((ext_vector_type(4))) int i32x4;
typedef unsigned short u16;

__device__ __forceinline__ float bf2f(u16 b) {
  unsigned u = ((unsigned)b) << 16;
  return __builtin_bit_cast(float, u);
}
__device__ __forceinline__ f16x8 cvt8(i32x4 v) {
  f16x8 r;
#pragma unroll
  for (int i = 0; i < 4; ++i) {
    unsigned u = __builtin_bit_cast(unsigned, v[i]);
    r[2 * i]     = (f16)__builtin_bit_cast(float, (u & 0xffffu) << 16);
    r[2 * i + 1] = (f16)__builtin_bit_cast(float, u & 0xffff0000u);
  }
  return r;
}

// HBM -> LDS direct DMA, 16 B/lane. LDS dest is wave-uniform base + lane*16.
__device__ __forceinline__ void gload16(const void* g, void* l) {
  __builtin_amdgcn_global_load_lds(
      (const __attribute__((address_space(1))) unsigned*)g,
      (__attribute__((address_space(3))) unsigned*)l, 16, 0, 0);
}

// ---------------- kernel 0: input dtype detection (EVEN u16 parity) ----
__global__ __launch_bounds__(64) void detect_kernel(const u16* __restrict__ h16,
                                                    int* __restrict__ flag)
{
  int lane = threadIdx.x;
  unsigned u = h16[lane * 2];
  unsigned e = (u >> 7) & 0xFFu;
  int sane = (e >= 0x60u && e <= 0x8Eu) ? 1 : 0;
#pragma unroll
  for (int off = 32; off >= 1; off >>= 1) sane += __shfl_xor(sane, off);
  if (lane == 0) *flag = (sane >= 32) ? 1 : 0;  // 1 = bf16 inputs, 0 = fp32
}

// ---------------- kernel 0.5: ws-too-small sentinel ----------------
__global__ __launch_bounds__(256) void sentinel_kernel(float* __restrict__ out) {
  int i = blockIdx.x * 256 + threadIdx.x;
  if (i < N_TOK * 128) out[i] = 100.0f;
}

// ---------------- kernel 1: W transpose -> fp16 ----------------
// W_query additionally scaled by log2(e): scores arrive in log2 domain
// (leakyrelu commutes with positive scaling), so softmax uses exp2 directly.
__global__ __launch_bounds__(256) void wt_kernel(
    const int* __restrict__ flag,
    const void* __restrict__ Wq, const void* __restrict__ Wk,
    const void* __restrict__ Wv, f16* __restrict__ Wt)
{
  const int isbf = *flag;
  int w = blockIdx.y;
  const void* W = (w == 0) ? Wq : (w == 1) ? Wk : Wv;
  int idx = blockIdx.x * 256 + threadIdx.x;
  int k = idx >> 7, n = idx & 127;
  float v = isbf ? bf2f(((const u16*)W)[idx]) : ((const float*)W)[idx];
  if (w == 0) v *= LOG2E;
  Wt[w * 32768 + n * 256 + k] = (f16)v;
}

// ---------------- kernel 2: fused QKV GEMM ----------------
__global__ __launch_bounds__(256) void qkv_kernel(
    const int* __restrict__ flag, const void* __restrict__ hvp,
    const f16* __restrict__ Wt,
    f16* __restrict__ Qo, f16* __restrict__ Ko, f16* __restrict__ Vt)
{
  const int isbf = *flag;
  const int mb = blockIdx.x * 64;
  const int gy = blockIdx.y;
  const int tid = threadIdx.x;
  const int wave = tid >> 6, lane = tid & 63, quad = lane >> 4, l16 = lane & 15;

  __shared__ __align__(16) f16 hs[64][256 + 8];

  if (isbf) {
    const u16* h = (const u16*)hvp;
#pragma unroll
    for (int i = 0; i < 8; ++i) {
      int c = i * 256 + tid;
      int r = c >> 5, o = c & 31;
      i32x4 v = *(const i32x4*)(h + (size_t)(mb + r) * 256 + o * 8);
      *(f16x8*)(&hs[r][o * 8]) = cvt8(v);
    }
  } else {
    const float* h = (const float*)hvp;
#pragma unroll
    for (int i = 0; i < 8; ++i) {
      int c = i * 256 + tid;
      int r = c >> 5, o = c & 31;
      const float* p = h + (size_t)(mb + r) * 256 + o * 8;
      f32x4 v0 = *(const f32x4*)p, v1 = *(const f32x4*)(p + 4);
      f16x8 q;
#pragma unroll
      for (int j = 0; j < 4; ++j) { q[j] = (f16)v0[j]; q[4 + j] = (f16)v1[j]; }
      *(f16x8*)(&hs[r][o * 8]) = q;
    }
  }
  __syncthreads();

  const f16* Wg = Wt + gy * 32768;

  if (gy < 2) {
    f16x8 a[8];
#pragma unroll
    for (int ks = 0; ks < 8; ++ks)
      a[ks] = *(const f16x8*)(&hs[wave * 16 + l16][ks * 32 + quad * 8]);
    f32x4 acc[8];
#pragma unroll
    for (int ct = 0; ct < 8; ++ct) acc[ct] = (f32x4){0.f, 0.f, 0.f, 0.f};
#pragma unroll
    for (int ks = 0; ks < 8; ++ks)
#pragma unroll
      for (int ct = 0; ct < 8; ++ct) {
        f16x8 b = *(const f16x8*)(Wg + (ct * 16 + l16) * 256 + ks * 32 + quad * 8);
        acc[ct] = __builtin_amdgcn_mfma_f32_16x16x32_f16(a[ks], b, acc[ct], 0, 0, 0);
      }
    f16* O = (gy == 0) ? Qo : Ko;
#pragma unroll
    for (int ct = 0; ct < 8; ++ct)
#pragma unroll
      for (int r = 0; r < 4; ++r)
        O[(size_t)(mb + wave * 16 + quad * 4 + r) * 128 + ct * 16 + l16] = (f16)acc[ct][r];
  } else {
    f32x4 acc[2][4];
#pragma unroll
    for (int ft = 0; ft < 2; ++ft)
#pragma unroll
      for (int bt = 0; bt < 4; ++bt) acc[ft][bt] = (f32x4){0.f, 0.f, 0.f, 0.f};
#pragma unroll
    for (int ks = 0; ks < 8; ++ks) {
      f16x8 a2[2], b2[4];
#pragma unroll
      for (int ft = 0; ft < 2; ++ft)
        a2[ft] = *(const f16x8*)(Wg + ((wave * 2 + ft) * 16 + l16) * 256 + ks * 32 + quad * 8);
#pragma unroll
      for (int bt = 0; bt < 4; ++bt)
        b2[bt] = *(const f16x8*)(&hs[bt * 16 + l16][ks * 32 + quad * 8]);
#pragma unroll
      for (int ft = 0; ft < 2; ++ft)
#pragma unroll
        for (int bt = 0; bt < 4; ++bt)
          acc[ft][bt] = __builtin_amdgcn_mfma_f32_16x16x32_f16(a2[ft], b2[bt], acc[ft][bt], 0, 0, 0);
    }
#pragma unroll
    for (int ft = 0; ft < 2; ++ft)
#pragma unroll
      for (int bt = 0; bt < 4; ++bt)
#pragma unroll
        for (int r = 0; r < 4; ++r)
          Vt[(size_t)((wave * 2 + ft) * 16 + quad * 4 + r) * N_TOK + mb + bt * 16 + l16] =
              (f16)acc[ft][bt][r];
  }
}

// ---------------- kernel 3: flash attention, DMA + counted-vmcnt -------
// R12 = EXACT R10 (best, flash ~385us, total 1476) + s_setprio around the
// two MFMA clusters (T5; register-neutral; catalog +4-7% on phase-split
// attention).  R11's (256,4)/PsL-swizzle retired: cap 128 < live state
// ~140 -> spill, flash 565us.  REGISTER LAW FINAL: 3 waves/SIMD max.
// Loop: QK(t) -> [vmcnt(0) lgkm(0)] bar -> DMA K(t+1)+masks -> Ps/PV(t)
// -> [lgkm(0)] bar -> DMA V(t+1) -> vmcnt(4) -> bar.
// LDS 41984 B, (256,3) -> 3 blocks/CU.
__global__ __launch_bounds__(256, 3) void flash_kernel(
    const f16* __restrict__ Q, const f16* __restrict__ Kg,
    const f16* __restrict__ Vt, const int* __restrict__ adj,
    float* __restrict__ Opart, float* __restrict__ mpart,
    float* __restrict__ lpart)
{
  const int qb = blockIdx.x * 64;
  const int ksec = blockIdx.y;
  const int base = 256 / NSPLIT;                 // 85
  const int rem  = 256 % NSPLIT;                 // 1
  const int iters = base + (ksec < rem ? 1 : 0); // 86,85,85
  const int tile0 = ksec * base + (ksec < rem ? ksec : rem);
  const int kb0 = tile0 * 64;
  const int tid = threadIdx.x;
  const int wave = tid >> 6, lane = tid & 63, quad = lane >> 4, l16 = lane & 15;

  __shared__ __align__(16) f16 KsL[64 * 128];   // [row][128], 256 B rows
  __shared__ __align__(16) f16 VsL[128 * 64];   // [d][64], 128 B rows
  __shared__ __align__(16) f16 Ps[4][16][72];

  const int swl = (l16 & 7) << 4;  // read-side XOR

  f16x8 qf[4];
#pragma unroll
  for (int ks = 0; ks < 4; ++ks)
    qf[ks] = *(const f16x8*)(Q + (size_t)(qb + wave * 16 + l16) * 128 + ks * 32 + quad * 8);

  f16x8 ONES;
#pragma unroll
  for (int j = 0; j < 8; ++j) ONES[j] = (f16)1.0f;

  const int* aprow[4];
#pragma unroll
  for (int r = 0; r < 4; ++r)
    aprow[r] = adj + (size_t)(qb + wave * 16 + quad * 4 + r) * N_TOK + l16;

  f32x4 Oacc[8];
#pragma unroll
  for (int ot = 0; ot < 8; ++ot) Oacc[ot] = (f32x4){0.f, 0.f, 0.f, 0.f};
  f32x4 Lacc = (f32x4){0.f, 0.f, 0.f, 0.f};
  float m2[4];
#pragma unroll
  for (int r = 0; r < 4; ++r) m2[r] = -INFINITY;

  int am[4][4];

  const char* Kc = (const char*)Kg;
  const char* Vc = (const char*)Vt;
  char* Kl = (char*)KsL;
  char* Vl = (char*)VsL;

#define STAGE_K(KB)                                                           \
  {                                                                           \
    int kb_ = (KB);                                                           \
    _Pragma("unroll")                                                         \
    for (int i = 0; i < 4; ++i) {                                             \
      int row = i * 16 + (tid >> 4);                                          \
      int colb = ((tid & 15) * 16) ^ ((row & 7) << 4);                        \
      gload16(Kc + (size_t)(kb_ + row) * 256 + colb,                          \
              Kl + i * 4096 + wave * 1024);                                   \
    }                                                                         \
  }
#define STAGE_V(KB)                                                           \
  {                                                                           \
    int kb_ = (KB);                                                           \
    _Pragma("unroll")                                                         \
    for (int i = 0; i < 4; ++i) {                                             \
      int d = i * 32 + (tid >> 3);                                            \
      int colb = ((tid & 7) * 16) ^ ((d & 7) << 4);                           \
      gload16(Vc + (size_t)d * (N_TOK * 2) + (size_t)kb_ * 2 + colb,          \
              Vl + i * 4096 + wave * 1024);                                   \
    }                                                                         \
  }

  // -------- prologue: DMA tile0 + masks tile0, full drain --------
  STAGE_K(kb0);
  STAGE_V(kb0);
#pragma unroll
  for (int r = 0; r < 4; ++r)
#pragma unroll
    for (int ct = 0; ct < 4; ++ct)
      am[r][ct] = aprow[r][kb0 + ct * 16];
  asm volatile("s_waitcnt vmcnt(0)" ::: "memory");
  __builtin_amdgcn_s_barrier();
  asm volatile("" ::: "memory");

  for (int it = 0; it < iters; ++it) {
    const int kbn = kb0 + (it + 1) * 64;

    // --- QK^T from swizzled K tile; leakyrelu; mask from registers ---
    float sc[4][4];
    __builtin_amdgcn_s_setprio(1);
#pragma unroll
    for (int ct = 0; ct < 4; ++ct) {
      f32x4 s = (f32x4){0.f, 0.f, 0.f, 0.f};
#pragma unroll
      for (int ks = 0; ks < 4; ++ks) {
        f16x8 b = *(const f16x8*)((const char*)KsL + (ct * 16 + l16) * 256 +
                                  ((ks * 64 + quad * 16) ^ swl));
        s = __builtin_amdgcn_mfma_f32_16x16x32_f16(qf[ks], b, s, 0, 0, 0);
      }
#pragma unroll
      for (int r = 0; r < 4; ++r) {
        float v = s[r];
        v = fmaxf(v, ALPHA_LRELU * v);
        sc[ct][r] = (am[r][ct] > 0) ? v : NEGV;
      }
    }
    __builtin_amdgcn_s_setprio(0);

    // --- row max + defer-max rescale (register-only) ---
    float mx[4];
#pragma unroll
    for (int r = 0; r < 4; ++r) {
      float m = fmaxf(fmaxf(sc[0][r], sc[1][r]), fmaxf(sc[2][r], sc[3][r]));
#pragma unroll
      for (int off = 8; off >= 1; off >>= 1)
        m = fmaxf(m, __shfl_xor(m, off, 16));
      mx[r] = m;
    }
    bool up = (mx[0] > m2[0] + DEFER_THR) | (mx[1] > m2[1] + DEFER_THR) |
              (mx[2] > m2[2] + DEFER_THR) | (mx[3] > m2[3] + DEFER_THR);
    if (__ballot(up)) {
      float al[4];
#pragma unroll
      for (int r = 0; r < 4; ++r) {
        float mn = fmaxf(m2[r], mx[r]);
        al[r] = exp2f(m2[r] - mn);
        m2[r] = mn;
      }
#pragma unroll
      for (int ot = 0; ot < 8; ++ot)
#pragma unroll
        for (int r = 0; r < 4; ++r) Oacc[ot][r] *= al[r];
#pragma unroll
      for (int r = 0; r < 4; ++r) Lacc[r] *= al[r];
    }

    // --- barrier #1: Ks reads done everywhere; V(t) DMA writes visible ---
    asm volatile("s_waitcnt vmcnt(0) lgkmcnt(0)" ::: "memory");
    __builtin_amdgcn_s_barrier();
    asm volatile("" ::: "memory");

    // --- issue K(t+1) DMA (flies during PV) + mask prefetch ---
    if (it + 1 < iters) {
      STAGE_K(kbn);
#pragma unroll
      for (int r = 0; r < 4; ++r)
#pragma unroll
        for (int ct = 0; ct < 4; ++ct)
          am[r][ct] = aprow[r][kbn + ct * 16];
    }

    // --- P -> Ps, PV from Vs(t), Lacc ---
#pragma unroll
    for (int ct = 0; ct < 4; ++ct)
#pragma unroll
      for (int r = 0; r < 4; ++r)
        Ps[wave][quad * 4 + r][ct * 16 + l16] = (f16)exp2f(sc[ct][r] - m2[r]);

    asm volatile("s_waitcnt lgkmcnt(0)" ::: "memory");
    f16x8 pa0 = *(const f16x8*)(&Ps[wave][l16][quad * 8]);
    f16x8 pa1 = *(const f16x8*)(&Ps[wave][l16][32 + quad * 8]);
    __builtin_amdgcn_s_setprio(1);
#pragma unroll
    for (int ot = 0; ot < 8; ++ot) {
      const char* vrow = (const char*)VsL + (ot * 16 + l16) * 128;
      f16x8 b0 = *(const f16x8*)(vrow + ((quad * 16) ^ swl));
      f16x8 b1 = *(const f16x8*)(vrow + ((64 + quad * 16) ^ swl));
      Oacc[ot] = __builtin_amdgcn_mfma_f32_16x16x32_f16(pa0, b0, Oacc[ot], 0, 0, 0);
      Oacc[ot] = __builtin_amdgcn_mfma_f32_16x16x32_f16(pa1, b1, Oacc[ot], 0, 0, 0);
    }
    Lacc = __builtin_amdgcn_mfma_f32_16x16x32_f16(pa0, ONES, Lacc, 0, 0, 0);
    Lacc = __builtin_amdgcn_mfma_f32_16x16x32_f16(pa1, ONES, Lacc, 0, 0, 0);
    __builtin_amdgcn_s_setprio(0);

    // --- barrier #2: Vs reads done everywhere ---
    asm volatile("s_waitcnt lgkmcnt(0)" ::: "memory");
    __builtin_amdgcn_s_barrier();
    asm volatile("" ::: "memory");

    // --- issue V(t+1) DMA; retire K(t+1)+masks (leave V in flight) ---
    if (it + 1 < iters) {
      STAGE_V(kbn);
      asm volatile("s_waitcnt vmcnt(4)" ::: "memory");
    }

    // --- barrier #3: K(t+1) writes visible -> next QK may read ---
    __builtin_amdgcn_s_barrier();
    asm volatile("" ::: "memory");
  }
#undef STAGE_K
#undef STAGE_V

  float* Op = Opart + (size_t)ksec * (N_TOK * 128);
#pragma unroll
  for (int ot = 0; ot < 8; ++ot)
#pragma unroll
    for (int r = 0; r < 4; ++r) {
      int row = qb + wave * 16 + quad * 4 + r;
      Op[(size_t)row * 128 + ot * 16 + l16] = Oacc[ot][r];
    }
  if (l16 == 0) {
#pragma unroll
    for (int r = 0; r < 4; ++r) {
      int row = qb + wave * 16 + quad * 4 + r;
      mpart[ksec * N_TOK + row] = m2[r];   // log2-domain (deferred) max
      lpart[ksec * N_TOK + row] = Lacc[r];
    }
  }
}

// ---------------- kernel 4: split-K combine + elu (log2 domain) --------
__global__ __launch_bounds__(256) void combine_kernel(
    const float* __restrict__ Opart, const float* __restrict__ mpart,
    const float* __restrict__ lpart, float* __restrict__ out)
{
  const int qb = blockIdx.x * 64;
  const int t = threadIdx.x;
  __shared__ float sa[NSPLIT][64], sdn[64];
  if (t < 64) {
    float m = -INFINITY;
#pragma unroll
    for (int s = 0; s < NSPLIT; ++s) m = fmaxf(m, mpart[s * N_TOK + qb + t]);
    float dn = 0.f;
#pragma unroll
    for (int s = 0; s < NSPLIT; ++s) {
      float a = exp2f(mpart[s * N_TOK + qb + t] - m);
      sa[s][t] = a;
      dn += lpart[s * N_TOK + qb + t] * a;
    }
    sdn[t] = 1.0f / dn;
  }
  __syncthreads();
  float* Og = out + (size_t)qb * 128;
#pragma unroll
  for (int i = 0; i < 8; ++i) {
    int idx = (i * 256 + t) * 4;
    int row = idx >> 7;
    f32x4 acc = (f32x4){0.f, 0.f, 0.f, 0.f};
#pragma unroll
    for (int s = 0; s < NSPLIT; ++s) {
      f32x4 o = *(const f32x4*)(Opart + (size_t)s * (N_TOK * 128) + (size_t)qb * 128 + idx);
      float a = sa[s][row];
#pragma unroll
      for (int j = 0; j < 4; ++j) acc[j] += o[j] * a;
    }
    float dn = sdn[row];
    f32x4 v;
#pragma unroll
    for (int j = 0; j < 4; ++j) {
      float x = acc[j] * dn;
      v[j] = (x > 0.f) ? x : (__expf(x) - 1.f);
    }
    *(f32x4*)(Og + idx) = v;
  }
}

// ---------------- fallback: single-pass flash (ws too small) ----------
__global__ __launch_bounds__(256) void flash1_kernel(
    const f16* __restrict__ Q, const f16* __restrict__ Kg,
    const f16* __restrict__ Vt, const int* __restrict__ adj,
    float* __restrict__ out)
{
  const int qb = blockIdx.x * 64;
  const int tid = threadIdx.x;
  const int wave = tid >> 6, lane = tid & 63, quad = lane >> 4, l16 = lane & 15;

  __shared__ __align__(16) f16 Ks[64][136];
  __shared__ __align__(16) f16 Vs[128][72];
  __shared__ __align__(16) int As[64][68];
  __shared__ __align__(16) f16 Ps[4][16][72];

  f16x8 qf[4];
#pragma unroll
  for (int ks = 0; ks < 4; ++ks)
    qf[ks] = *(const f16x8*)(Q + (size_t)(qb + wave * 16 + l16) * 128 + ks * 32 + quad * 8);
  f16x8 ONES;
#pragma unroll
  for (int j = 0; j < 8; ++j) ONES[j] = (f16)1.0f;

  f32x4 Oacc[8];
#pragma unroll
  for (int ot = 0; ot < 8; ++ot) Oacc[ot] = (f32x4){0.f, 0.f, 0.f, 0.f};
  f32x4 Lacc = (f32x4){0.f, 0.f, 0.f, 0.f};
  float m2[4];
#pragma unroll
  for (int r = 0; r < 4; ++r) m2[r] = -INFINITY;

  i32x4 pK[4], pV[4], pA[4];
#pragma unroll
  for (int i = 0; i < 4; ++i) {
    int c = i * 256 + tid;
    pK[i] = *(const i32x4*)(Kg + (size_t)(c >> 4) * 128 + (c & 15) * 8);
    pV[i] = *(const i32x4*)(Vt + (size_t)(c >> 3) * N_TOK + (c & 7) * 8);
    pA[i] = *(const i32x4*)(adj + (size_t)(qb + (c >> 4)) * N_TOK + (c & 15) * 4);
  }

  for (int it = 0; it < 256; ++it) {
    __syncthreads();
#pragma unroll
    for (int i = 0; i < 4; ++i) {
      int c = i * 256 + tid;
      *(f16x8*)(&Ks[c >> 4][(c & 15) * 8]) = __builtin_bit_cast(f16x8, pK[i]);
      *(f16x8*)(&Vs[c >> 3][(c & 7) * 8])  = __builtin_bit_cast(f16x8, pV[i]);
      *(i32x4*)(&As[c >> 4][(c & 15) * 4]) = pA[i];
    }
    __syncthreads();
    if (it + 1 < 256) {
      int kb = (it + 1) * 64;
#pragma unroll
      for (int i = 0; i < 4; ++i) {
        int c = i * 256 + tid;
        pK[i] = *(const i32x4*)(Kg + (size_t)(kb + (c >> 4)) * 128 + (c & 15) * 8);
        pV[i] = *(const i32x4*)(Vt + (size_t)(c >> 3) * N_TOK + kb + (c & 7) * 8);
        pA[i] = *(const i32x4*)(adj + (size_t)(qb + (c >> 4)) * N_TOK + kb + (c & 15) * 4);
      }
    }
    float sc[4][4];
#pragma unroll
    for (int ct = 0; ct < 4; ++ct) {
      f32x4 s = (f32x4){0.f, 0.f, 0.f, 0.f};
#pragma unroll
      for (int ks = 0; ks < 4; ++ks) {
        f16x8 b = *(const f16x8*)(&Ks[ct * 16 + l16][ks * 32 + quad * 8]);
        s = __builtin_amdgcn_mfma_f32_16x16x32_f16(qf[ks], b, s, 0, 0, 0);
      }
#pragma unroll
      for (int r = 0; r < 4; ++r) {
        float v = s[r];
        v = fmaxf(v, ALPHA_LRELU * v);
        sc[ct][r] = (As[wave * 16 + quad * 4 + r][ct * 16 + l16] > 0) ? v : NEGV;
      }
    }
    float mx[4];
#pragma unroll
    for (int r = 0; r < 4; ++r) {
      float m = fmaxf(fmaxf(sc[0][r], sc[1][r]), fmaxf(sc[2][r], sc[3][r]));
#pragma unroll
      for (int off = 8; off >= 1; off >>= 1)
        m = fmaxf(m, __shfl_xor(m, off, 16));
      mx[r] = m;
    }
    bool up = (mx[0] > m2[0] + DEFER_THR) | (mx[1] > m2[1] + DEFER_THR) |
              (mx[2] > m2[2] + DEFER_THR) | (mx[3] > m2[3] + DEFER_THR);
    if (__ballot(up)) {
      float al[4];
#pragma unroll
      for (int r = 0; r < 4; ++r) {
        float mn = fmaxf(m2[r], mx[r]);
        al[r] = exp2f(m2[r] - mn);
        m2[r] = mn;
      }
#pragma unroll
      for (int ot = 0; ot < 8; ++ot)
#pragma unroll
        for (int r = 0; r < 4; ++r) Oacc[ot][r] *= al[r];
#pragma unroll
      for (int r = 0; r < 4; ++r) Lacc[r] *= al[r];
    }
#pragma unroll
    for (int ct = 0; ct < 4; ++ct)
#pragma unroll
      for (int r = 0; r < 4; ++r)
        Ps[wave][quad * 4 + r][ct * 16 + l16] = (f16)exp2f(sc[ct][r] - m2[r]);

    asm volatile("s_waitcnt lgkmcnt(0)" ::: "memory");
    f16x8 pa0 = *(const f16x8*)(&Ps[wave][l16][quad * 8]);
    f16x8 pa1 = *(const f16x8*)(&Ps[wave][l16][32 + quad * 8]);
#pragma unroll
    for (int ot = 0; ot < 8; ++ot) {
      f16x8 b0 = *(const f16x8*)(&Vs[ot * 16 + l16][quad * 8]);
      f16x8 b1 = *(const f16x8*)(&Vs[ot * 16 + l16][32 + quad * 8]);
      Oacc[ot] = __builtin_amdgcn_mfma_f32_16x16x32_f16(pa0, b0, Oacc[ot], 0, 0, 0);
      Oacc[ot] = __builtin_amdgcn_mfma_f32_16x16x32_f16(pa1, b1, Oacc[ot], 0, 0, 0);
    }
    Lacc = __builtin_amdgcn_mfma_f32_16x16x32_f16(pa0, ONES, Lacc, 0, 0, 0);
    Lacc = __builtin_amdgcn_mfma_f32_16x16x32_f16(pa1, ONES, Lacc, 0, 0, 0);
  }
#pragma unroll
  for (int ot = 0; ot < 8; ++ot)
#pragma unroll
    for (int r = 0; r < 4; ++r) {
      float v = Oacc[ot][r] / Lacc[r];
      v = (v > 0.f) ? v : (__expf(v) - 1.f);
      int row = qb + wave * 16 + quad * 4 + r;
      out[(size_t)row * 128 + ot * 16 + l16] = v;
    }
}

extern "C" void kernel_launch(void* const* d_in, const int* in_sizes, int n_in,
                              void* d_out, int out_size, void* d_ws, size_t ws_size,
                              hipStream_t stream)
{
  const void* h  = d_in[0];
  const int* adj = (const int*)d_in[1];
  const void* Wq = d_in[2];
  const void* Wk = d_in[3];
  const void* Wv = d_in[4];
  float* out = (float*)d_out;             // fp32 [16384][128]

  char* ws = (char*)d_ws;
  int* flag = (int*)ws;                    // @0
  f16* Wt = (f16*)(ws + 1024);             // 196608 B
  f16* Q  = (f16*)(ws + 262144);           // 4 MiB
  f16* K  = (f16*)(ws + 4456448);          // 4 MiB
  f16* Vt = (f16*)(ws + 8650752);          // 4 MiB -> 12845056
  float* Opart = (float*)(ws + 12845056);  // 3 x 16384 x 128 f32 = 24 MiB
  float* mpart = (float*)(ws + 38010880);  // 3 x 16384 f32
  float* lpart = (float*)(ws + 38207488);  // 3 x 16384 f32 -> 38404096
  const size_t NEED_BASE  = 12845056;
  const size_t NEED_SPLIT = 38404096;

  if (ws_size < NEED_BASE) {
    sentinel_kernel<<<(N_TOK * 128 + 255) / 256, 256, 0, stream>>>(out);
    return;
  }

  detect_kernel<<<1, 64, 0, stream>>>((const u16*)h, flag);
  wt_kernel<<<dim3(128, 3), 256, 0, stream>>>(flag, Wq, Wk, Wv, Wt);
  qkv_kernel<<<dim3(256, 3), 256, 0, stream>>>(flag, h, Wt, Q, K, Vt);

  if (ws_size >= NEED_SPLIT) {
    // split-K x3: 768 blocks = 3 resident/CU, DMA staging, counted vmcnt
    flash_kernel<<<dim3(256, NSPLIT), 256, 0, stream>>>(Q, K, Vt, adj,
                                                        Opart, mpart, lpart);
    combine_kernel<<<dim3(256), 256, 0, stream>>>(Opart, mpart, lpart, out);
  } else {
    flash1_kernel<<<dim3(256), 256, 0, stream>>>(Q, K, Vt, adj, out);
  }
}